// Round 1
// baseline (96604.901 us; speedup 1.0000x reference)
//
#include <hip/hip_runtime.h>
#include <hip/hip_bf16.h>

// 2-layer GRU encoder, T=4096, H=1024.
// Phase plan: embed gather -> [gemm gi -> persistent scan] x 2 layers.
// Scan: 64 persistent WGs (1/CU), W_hh resident in VGPRs, per-step
// device-scope barrier (counter per step), h double-buffered in ws.

#define TT    4096
#define HDIM  1024
#define GWG   64      // workgroups in scan (must divide HDIM/16)
#define SBS   256     // scan block size (4 waves)

// ---------------- embedding gather ----------------
__global__ void embed_kernel(const int* __restrict__ idx,
                             const float* __restrict__ emb,
                             float* __restrict__ x) {
    int t = blockIdx.x;
    int row = idx[t];
    const float4* src = reinterpret_cast<const float4*>(emb + (size_t)row * HDIM);
    float4* dst = reinterpret_cast<float4*>(x + (size_t)t * HDIM);
    dst[threadIdx.x] = src[threadIdx.x];   // 256 threads x 16B = 4KB row
}

// ---------------- fp32 NT GEMM: C[M,N] = A[M,K] * B[N,K]^T + bias[N] ----------------
// BM=BN=64, BK=32, 256 threads, 4x4 micro-tile.
#define BM 64
#define BN 64
#define BK 32
__global__ __launch_bounds__(256)
void gemm_nt_bias(const float* __restrict__ A,
                  const float* __restrict__ Bw,
                  const float* __restrict__ bias,
                  float* __restrict__ C,
                  int M, int N, int K) {
    __shared__ float As[BK][BM];
    __shared__ float Bs[BK][BN];
    const int tid = threadIdx.x;
    const int m0 = blockIdx.x * BM;
    const int n0 = blockIdx.y * BN;
    const int tx = tid & 15, ty = tid >> 4;
    const int lr = tid >> 3;          // 0..31
    const int lc = (tid & 7) * 4;     // k offset 0..28

    float acc[4][4] = {};

    for (int k0 = 0; k0 < K; k0 += BK) {
#pragma unroll
        for (int pass = 0; pass < 2; ++pass) {
            int m = lr + pass * 32;
            float4 v = *reinterpret_cast<const float4*>(A + (size_t)(m0 + m) * K + k0 + lc);
            As[lc + 0][m] = v.x; As[lc + 1][m] = v.y;
            As[lc + 2][m] = v.z; As[lc + 3][m] = v.w;
            float4 u = *reinterpret_cast<const float4*>(Bw + (size_t)(n0 + m) * K + k0 + lc);
            Bs[lc + 0][m] = u.x; Bs[lc + 1][m] = u.y;
            Bs[lc + 2][m] = u.z; Bs[lc + 3][m] = u.w;
        }
        __syncthreads();
#pragma unroll
        for (int kk = 0; kk < BK; ++kk) {
            float4 a = *reinterpret_cast<const float4*>(&As[kk][ty * 4]);
            float4 b = *reinterpret_cast<const float4*>(&Bs[kk][tx * 4]);
            float av[4] = {a.x, a.y, a.z, a.w};
            float bv[4] = {b.x, b.y, b.z, b.w};
#pragma unroll
            for (int i = 0; i < 4; ++i)
#pragma unroll
                for (int j = 0; j < 4; ++j)
                    acc[i][j] = fmaf(av[i], bv[j], acc[i][j]);
        }
        __syncthreads();
    }

    float4 b4 = *reinterpret_cast<const float4*>(bias + n0 + tx * 4);
    float bb[4] = {b4.x, b4.y, b4.z, b4.w};
#pragma unroll
    for (int i = 0; i < 4; ++i) {
        int m = m0 + ty * 4 + i;
        float4 o;
        o.x = acc[i][0] + bb[0];
        o.y = acc[i][1] + bb[1];
        o.z = acc[i][2] + bb[2];
        o.w = acc[i][3] + bb[3];
        *reinterpret_cast<float4*>(C + (size_t)m * N + n0 + tx * 4) = o;
    }
}

// ---------------- persistent GRU scan ----------------
// WG g owns hidden slice j in [g*16, g*16+16)  -> 48 gh rows (3 gates x 16).
// Row slot s in [0,48): q = s>>4 (gate), jl = s&15. Row = q*H + g*16 + jl.
// Wave w handles slots w*12 .. w*12+11; within wave: sub = lane>>4 picks one of
// 4 concurrent slots, l16 = lane&15 picks k-chunk [l16*64, l16*64+64).
__global__ __launch_bounds__(SBS, 1)
void gru_scan(const float* __restrict__ gi,    // [T,3H]
              const float* __restrict__ whh,   // [3H,H]
              const float* __restrict__ bhh,   // [3H]
              float* __restrict__ ys,          // [T,H]
              float* __restrict__ hfin,        // [H]
              float* h_buf,                    // [2][H]
              unsigned* cnt) {                 // [T]
    const int g    = blockIdx.x;
    const int tid  = threadIdx.x;
    const int w    = tid >> 6;
    const int lane = tid & 63;
    const int sub  = lane >> 4;
    const int l16  = lane & 15;

    // Load resident W_hh slice: 3 slots x 64 k-elems per lane = 192 VGPRs.
    float Wreg[3][64];
#pragma unroll
    for (int i = 0; i < 3; ++i) {
        int slot = w * 12 + i * 4 + sub;
        int q = slot >> 4, jl = slot & 15;
        const float* wrow = whh + (size_t)(q * HDIM + g * 16 + jl) * HDIM + l16 * 64;
#pragma unroll
        for (int k4 = 0; k4 < 16; ++k4) {
            float4 v = reinterpret_cast<const float4*>(wrow)[k4];
            Wreg[i][k4 * 4 + 0] = v.x;
            Wreg[i][k4 * 4 + 1] = v.y;
            Wreg[i][k4 * 4 + 2] = v.z;
            Wreg[i][k4 * 4 + 3] = v.w;
        }
    }

    float bh0 = 0.f, bh1 = 0.f, bh2 = 0.f;
    if (tid < 16) {
        bh0 = bhh[0 * HDIM + g * 16 + tid];
        bh1 = bhh[1 * HDIM + g * 16 + tid];
        bh2 = bhh[2 * HDIM + g * 16 + tid];
    }

    __shared__ float lds_gh[48];

    for (int t = 0; t < TT; ++t) {
        const int cur = t & 1, nxt = cur ^ 1;

        // h_t -> registers (agent-scope loads: coherent across XCDs)
        float hreg[64];
        float* hb = h_buf + cur * HDIM + l16 * 64;
#pragma unroll
        for (int kk = 0; kk < 64; ++kk)
            hreg[kk] = __hip_atomic_load(hb + kk, __ATOMIC_RELAXED, __HIP_MEMORY_SCOPE_AGENT);

        // partial dot products
        float p[3];
#pragma unroll
        for (int i = 0; i < 3; ++i) {
            float s = 0.f;
#pragma unroll
            for (int kk = 0; kk < 64; ++kk)
                s = fmaf(Wreg[i][kk], hreg[kk], s);
            p[i] = s;
        }
        // reduce across the 16-lane k groups
#pragma unroll
        for (int i = 0; i < 3; ++i) {
            float s = p[i];
            s += __shfl_xor(s, 1);
            s += __shfl_xor(s, 2);
            s += __shfl_xor(s, 4);
            s += __shfl_xor(s, 8);
            p[i] = s;
        }
        if (l16 == 0) {
#pragma unroll
            for (int i = 0; i < 3; ++i)
                lds_gh[w * 12 + i * 4 + sub] = p[i];
        }
        __syncthreads();

        if (tid < 16) {
            const int gj = g * 16 + tid;
            float hr = lds_gh[tid]      + bh0;
            float hz = lds_gh[16 + tid] + bh1;
            float hn = lds_gh[32 + tid] + bh2;
            const float* git = gi + (size_t)t * 3 * HDIM;
            float ir = git[gj];
            float iz = git[HDIM + gj];
            float in_ = git[2 * HDIM + gj];
            float h_old = __hip_atomic_load(h_buf + cur * HDIM + gj,
                                            __ATOMIC_RELAXED, __HIP_MEMORY_SCOPE_AGENT);
            float r = 1.f / (1.f + expf(-(ir + hr)));
            float z = 1.f / (1.f + expf(-(iz + hz)));
            float n = tanhf(in_ + r * hn);
            float h_new = (1.f - z) * n + z * h_old;
            __hip_atomic_store(h_buf + nxt * HDIM + gj, h_new,
                               __ATOMIC_RELAXED, __HIP_MEMORY_SCOPE_AGENT);
            ys[(size_t)t * HDIM + gj] = h_new;
            if (t == TT - 1) hfin[gj] = h_new;
        }

        // grid barrier for step t
        __syncthreads();
        if (tid == 0) {
            __threadfence();
            __hip_atomic_fetch_add(cnt + t, 1u, __ATOMIC_RELEASE, __HIP_MEMORY_SCOPE_AGENT);
            while (__hip_atomic_load(cnt + t, __ATOMIC_ACQUIRE, __HIP_MEMORY_SCOPE_AGENT) < GWG)
                __builtin_amdgcn_s_sleep(2);
        }
        __syncthreads();
    }
}

// ---------------- launch ----------------
extern "C" void kernel_launch(void* const* d_in, const int* in_sizes, int n_in,
                              void* d_out, int out_size, void* d_ws, size_t ws_size,
                              hipStream_t stream) {
    const int*   idx = (const int*)d_in[0];
    const float* emb = (const float*)d_in[1];
    const float* wih = (const float*)d_in[2];
    const float* whh = (const float*)d_in[3];
    const float* bih = (const float*)d_in[4];
    const float* bhh = (const float*)d_in[5];
    float* out = (float*)d_out;

    float* x    = (float*)d_ws;                 // [T,H]
    float* gi   = x   + (size_t)TT * HDIM;      // [T,3H]  (reused both layers)
    float* ys0  = gi  + (size_t)TT * 3 * HDIM;  // [T,H]
    float* ctrl = ys0 + (size_t)TT * HDIM;
    float* hbuf0 = ctrl;                        // [2,H]
    float* hbuf1 = hbuf0 + 2 * HDIM;            // [2,H]
    unsigned* cnt0 = (unsigned*)(hbuf1 + 2 * HDIM);  // [T]
    unsigned* cnt1 = cnt0 + TT;                      // [T]
    size_t ctrl_bytes = (size_t)(4 * HDIM) * 4 + (size_t)(2 * TT) * 4;

    hipMemsetAsync(ctrl, 0, ctrl_bytes, stream);

    embed_kernel<<<TT, 256, 0, stream>>>(idx, emb, x);

    const size_t wstride = (size_t)3 * HDIM * HDIM;
    const size_t bstride = (size_t)3 * HDIM;

    // layer 0
    gemm_nt_bias<<<dim3(TT / BM, 3 * HDIM / BN), 256, 0, stream>>>(
        x, wih, bih, gi, TT, 3 * HDIM, HDIM);
    gru_scan<<<GWG, SBS, 0, stream>>>(gi, whh, bhh, ys0,
                                      out + (size_t)TT * HDIM, hbuf0, cnt0);
    // layer 1 (outputs straight into d_out)
    gemm_nt_bias<<<dim3(TT / BM, 3 * HDIM / BN), 256, 0, stream>>>(
        ys0, wih + wstride, bih + bstride, gi, TT, 3 * HDIM, HDIM);
    gru_scan<<<GWG, SBS, 0, stream>>>(gi, whh + wstride, bhh + bstride, out,
                                      out + (size_t)TT * HDIM + HDIM, hbuf1, cnt1);
}

// Round 2
// 42216.696 us; speedup vs baseline: 2.2883x; 2.2883x over previous
//
#include <hip/hip_runtime.h>
#include <hip/hip_bf16.h>

// 2-layer GRU encoder, T=4096, H=1024.
// embed -> [gemm gi -> persistent scan] x 2.
// Scan v2: 64 WGs x 512 thr. W_hh in VGPRs (2x float4[16]/lane, static idx).
// h exchange: coherent 8B loads -> LDS. gi prefetched 1 step ahead.
// Per-step grid barrier via per-t counter in ws.

#define TT    4096
#define HDIM  1024
#define GWG   64
#define SBS   512

// ---------------- embedding gather ----------------
__global__ void embed_kernel(const int* __restrict__ idx,
                             const float* __restrict__ emb,
                             float* __restrict__ x) {
    int t = blockIdx.x;
    int row = idx[t];
    const float4* src = reinterpret_cast<const float4*>(emb + (size_t)row * HDIM);
    float4* dst = reinterpret_cast<float4*>(x + (size_t)t * HDIM);
    dst[threadIdx.x] = src[threadIdx.x];
}

// ---------------- fp32 NT GEMM: C[M,N] = A[M,K] * B[N,K]^T + bias[N] ----------------
#define BM 64
#define BN 64
#define BK 32
__global__ __launch_bounds__(256)
void gemm_nt_bias(const float* __restrict__ A,
                  const float* __restrict__ Bw,
                  const float* __restrict__ bias,
                  float* __restrict__ C,
                  int M, int N, int K) {
    __shared__ float As[BK][BM];
    __shared__ float Bs[BK][BN];
    const int tid = threadIdx.x;
    const int m0 = blockIdx.x * BM;
    const int n0 = blockIdx.y * BN;
    const int tx = tid & 15, ty = tid >> 4;
    const int lr = tid >> 3;
    const int lc = (tid & 7) * 4;

    float acc[4][4] = {};

    for (int k0 = 0; k0 < K; k0 += BK) {
#pragma unroll
        for (int pass = 0; pass < 2; ++pass) {
            int m = lr + pass * 32;
            float4 v = *reinterpret_cast<const float4*>(A + (size_t)(m0 + m) * K + k0 + lc);
            As[lc + 0][m] = v.x; As[lc + 1][m] = v.y;
            As[lc + 2][m] = v.z; As[lc + 3][m] = v.w;
            float4 u = *reinterpret_cast<const float4*>(Bw + (size_t)(n0 + m) * K + k0 + lc);
            Bs[lc + 0][m] = u.x; Bs[lc + 1][m] = u.y;
            Bs[lc + 2][m] = u.z; Bs[lc + 3][m] = u.w;
        }
        __syncthreads();
#pragma unroll
        for (int kk = 0; kk < BK; ++kk) {
            float4 a = *reinterpret_cast<const float4*>(&As[kk][ty * 4]);
            float4 b = *reinterpret_cast<const float4*>(&Bs[kk][tx * 4]);
            float av[4] = {a.x, a.y, a.z, a.w};
            float bv[4] = {b.x, b.y, b.z, b.w};
#pragma unroll
            for (int i = 0; i < 4; ++i)
#pragma unroll
                for (int j = 0; j < 4; ++j)
                    acc[i][j] = fmaf(av[i], bv[j], acc[i][j]);
        }
        __syncthreads();
    }

    float4 b4 = *reinterpret_cast<const float4*>(bias + n0 + tx * 4);
    float bb[4] = {b4.x, b4.y, b4.z, b4.w};
#pragma unroll
    for (int i = 0; i < 4; ++i) {
        int m = m0 + ty * 4 + i;
        float4 o;
        o.x = acc[i][0] + bb[0];
        o.y = acc[i][1] + bb[1];
        o.z = acc[i][2] + bb[2];
        o.w = acc[i][3] + bb[3];
        *reinterpret_cast<float4*>(C + (size_t)m * N + n0 + tx * 4) = o;
    }
}

// ---------------- persistent GRU scan v2 ----------------
// WG g owns h units [g*16, g*16+16) -> 48 gh rows. 512 threads.
// slot = tid>>3 (0..63; 48 active), l8 = tid&7. Lane's W chunk: float4 indices
// {k4*8 + l8 : k4 in [0,32)} of the row -> interleaved, LDS-conflict-free.
__device__ __forceinline__ float dot4(float4 a, float4 b) {
    return fmaf(a.x, b.x, fmaf(a.y, b.y, fmaf(a.z, b.z, a.w * b.w)));
}

__global__ __launch_bounds__(SBS, 1)
void gru_scan(const float* __restrict__ gi,    // [T,3H]
              const float* __restrict__ whh,   // [3H,H]
              const float* __restrict__ bhh,   // [3H]
              float* __restrict__ ys,          // [T,H]
              float* __restrict__ hfin,        // [H]
              float* h_buf,                    // [2][H] coherent
              unsigned* cnt) {                 // [T]
    const int g    = blockIdx.x;
    const int tid  = threadIdx.x;
    const int slot = tid >> 3;   // 0..63
    const int l8   = tid & 7;

    __shared__ float lds_h[HDIM];
    __shared__ float lds_gh[48];

    // ---- load W_hh slice into registers (static indices; no spill) ----
    float4 Wlo[16], Whi[16];
    if (slot < 48) {
        const int q = slot >> 4, jl = slot & 15;
        const float4* row4 = reinterpret_cast<const float4*>(
            whh + (size_t)(q * HDIM + g * 16 + jl) * HDIM);
#pragma unroll
        for (int k4 = 0; k4 < 16; ++k4) Wlo[k4] = row4[k4 * 8 + l8];
#pragma unroll
        for (int k4 = 0; k4 < 16; ++k4) Whi[k4] = row4[(k4 + 16) * 8 + l8];
    } else {
#pragma unroll
        for (int k4 = 0; k4 < 16; ++k4) { Wlo[k4] = float4{0,0,0,0}; Whi[k4] = float4{0,0,0,0}; }
    }

    float bh0 = 0.f, bh1 = 0.f, bh2 = 0.f;
    float gir = 0.f, giz = 0.f, gin = 0.f;
    if (tid < 16) {
        const int gj = g * 16 + tid;
        bh0 = bhh[0 * HDIM + gj];
        bh1 = bhh[1 * HDIM + gj];
        bh2 = bhh[2 * HDIM + gj];
        gir = gi[gj];
        giz = gi[HDIM + gj];
        gin = gi[2 * HDIM + gj];
    }

    // h_0 = 0
    lds_h[tid] = 0.f;
    lds_h[tid + SBS] = 0.f;
    __syncthreads();

    const float4* lh4 = reinterpret_cast<const float4*>(lds_h);

    for (int t = 0; t < TT; ++t) {
        // prefetch gi[t+1] (independent of h; hidden under this step)
        float nir = 0.f, niz = 0.f, nin = 0.f;
        if (tid < 16 && t + 1 < TT) {
            const float* base = gi + (size_t)(t + 1) * 3 * HDIM + g * 16 + tid;
            nir = base[0];
            niz = base[HDIM];
            nin = base[2 * HDIM];
        }

        // ---- phase A: 48 row-dots (8 lanes per row) ----
        if (slot < 48) {
            float p0 = 0.f, p1 = 0.f;
#pragma unroll
            for (int k4 = 0; k4 < 16; ++k4) p0 = fmaf(1.f, dot4(Wlo[k4], lh4[k4 * 8 + l8]), p0);
#pragma unroll
            for (int k4 = 0; k4 < 16; ++k4) p1 = fmaf(1.f, dot4(Whi[k4], lh4[(k4 + 16) * 8 + l8]), p1);
            float p = p0 + p1;
            p += __shfl_xor(p, 1);
            p += __shfl_xor(p, 2);
            p += __shfl_xor(p, 4);
            if (l8 == 0) lds_gh[slot] = p;
        }
        __syncthreads();   // S1: lds_gh ready

        // ---- phase B: gates + h store (wave 0, lanes 0..15) ----
        if (tid < 16) {
            const int gj = g * 16 + tid;
            const float hr = lds_gh[tid]      + bh0;
            const float hz = lds_gh[16 + tid] + bh1;
            const float hn = lds_gh[32 + tid] + bh2;
            const float h_old = lds_h[gj];
            const float r = 1.f / (1.f + expf(-(gir + hr)));
            const float z = 1.f / (1.f + expf(-(giz + hz)));
            const float n = tanhf(gin + r * hn);
            const float h_new = (1.f - z) * n + z * h_old;
            __hip_atomic_store(h_buf + ((t + 1) & 1) * HDIM + gj, h_new,
                               __ATOMIC_RELAXED, __HIP_MEMORY_SCOPE_AGENT);
            ys[(size_t)t * HDIM + gj] = h_new;
            if (t == TT - 1) hfin[gj] = h_new;
        }
        // arrive (lane 0 of wave 0; vmcnt covers this wave's h stores)
        if (tid == 0) {
            __threadfence();
            __hip_atomic_fetch_add(cnt + t, 1u, __ATOMIC_RELEASE, __HIP_MEMORY_SCOPE_AGENT);
            while (__hip_atomic_load(cnt + t, __ATOMIC_ACQUIRE, __HIP_MEMORY_SCOPE_AGENT) < GWG)
                __builtin_amdgcn_s_sleep(2);
        }
        __syncthreads();   // S2: barrier passed

        // ---- phase D: pull h_{t+1} into LDS (8B coherent load/thread) ----
        {
            const unsigned long long hv = __hip_atomic_load(
                reinterpret_cast<const unsigned long long*>(h_buf + ((t + 1) & 1) * HDIM) + tid,
                __ATOMIC_RELAXED, __HIP_MEMORY_SCOPE_AGENT);
            reinterpret_cast<unsigned long long*>(lds_h)[tid] = hv;
        }
        gir = nir; giz = niz; gin = nin;
        __syncthreads();   // S3: lds_h ready
    }
}

// ---------------- launch ----------------
extern "C" void kernel_launch(void* const* d_in, const int* in_sizes, int n_in,
                              void* d_out, int out_size, void* d_ws, size_t ws_size,
                              hipStream_t stream) {
    const int*   idx = (const int*)d_in[0];
    const float* emb = (const float*)d_in[1];
    const float* wih = (const float*)d_in[2];
    const float* whh = (const float*)d_in[3];
    const float* bih = (const float*)d_in[4];
    const float* bhh = (const float*)d_in[5];
    float* out = (float*)d_out;

    float* x    = (float*)d_ws;                 // [T,H]
    float* gi   = x   + (size_t)TT * HDIM;      // [T,3H]
    float* ys0  = gi  + (size_t)TT * 3 * HDIM;  // [T,H]
    float* ctrl = ys0 + (size_t)TT * HDIM;
    float* hbuf0 = ctrl;                        // [2,H]
    float* hbuf1 = hbuf0 + 2 * HDIM;            // [2,H]
    unsigned* cnt0 = (unsigned*)(hbuf1 + 2 * HDIM);  // [T]
    unsigned* cnt1 = cnt0 + TT;                      // [T]
    size_t ctrl_bytes = (size_t)(4 * HDIM) * 4 + (size_t)(2 * TT) * 4;

    hipMemsetAsync(ctrl, 0, ctrl_bytes, stream);

    embed_kernel<<<TT, 256, 0, stream>>>(idx, emb, x);

    const size_t wstride = (size_t)3 * HDIM * HDIM;
    const size_t bstride = (size_t)3 * HDIM;

    gemm_nt_bias<<<dim3(TT / BM, 3 * HDIM / BN), 256, 0, stream>>>(
        x, wih, bih, gi, TT, 3 * HDIM, HDIM);
    gru_scan<<<GWG, SBS, 0, stream>>>(gi, whh, bhh, ys0,
                                      out + (size_t)TT * HDIM, hbuf0, cnt0);

    gemm_nt_bias<<<dim3(TT / BM, 3 * HDIM / BN), 256, 0, stream>>>(
        ys0, wih + wstride, bih + bstride, gi, TT, 3 * HDIM, HDIM);
    gru_scan<<<GWG, SBS, 0, stream>>>(gi, whh + wstride, bhh + bstride, out,
                                      out + (size_t)TT * HDIM + HDIM, hbuf1, cnt1);
}

// Round 3
// 28242.734 us; speedup vs baseline: 3.4205x; 1.4948x over previous
//
#include <hip/hip_runtime.h>
#include <hip/hip_bf16.h>

// 2-layer GRU encoder, T=4096, H=1024.
// embed -> [gemm gi -> persistent scan] x 2.
// Scan v3: 64 WGs x 512 thr. W_hh in VGPRs. Flag-array grid barrier
// (per-WG 64B-padded seq flag, monotone; no atomic RMW serialization).

#define TT    4096
#define HDIM  1024
#define GWG   64
#define SBS   512
#define FSTR  16          // flag stride in words (64B)

// ---------------- embedding gather ----------------
__global__ void embed_kernel(const int* __restrict__ idx,
                             const float* __restrict__ emb,
                             float* __restrict__ x) {
    int t = blockIdx.x;
    int row = idx[t];
    const float4* src = reinterpret_cast<const float4*>(emb + (size_t)row * HDIM);
    float4* dst = reinterpret_cast<float4*>(x + (size_t)t * HDIM);
    dst[threadIdx.x] = src[threadIdx.x];
}

// ---------------- fp32 NT GEMM: C[M,N] = A[M,K] * B[N,K]^T + bias[N] ----------------
#define BM 64
#define BN 64
#define BK 32
__global__ __launch_bounds__(256)
void gemm_nt_bias(const float* __restrict__ A,
                  const float* __restrict__ Bw,
                  const float* __restrict__ bias,
                  float* __restrict__ C,
                  int M, int N, int K) {
    __shared__ float As[BK][BM];
    __shared__ float Bs[BK][BN];
    const int tid = threadIdx.x;
    const int m0 = blockIdx.x * BM;
    const int n0 = blockIdx.y * BN;
    const int tx = tid & 15, ty = tid >> 4;
    const int lr = tid >> 3;
    const int lc = (tid & 7) * 4;

    float acc[4][4] = {};

    for (int k0 = 0; k0 < K; k0 += BK) {
#pragma unroll
        for (int pass = 0; pass < 2; ++pass) {
            int m = lr + pass * 32;
            float4 v = *reinterpret_cast<const float4*>(A + (size_t)(m0 + m) * K + k0 + lc);
            As[lc + 0][m] = v.x; As[lc + 1][m] = v.y;
            As[lc + 2][m] = v.z; As[lc + 3][m] = v.w;
            float4 u = *reinterpret_cast<const float4*>(Bw + (size_t)(n0 + m) * K + k0 + lc);
            Bs[lc + 0][m] = u.x; Bs[lc + 1][m] = u.y;
            Bs[lc + 2][m] = u.z; Bs[lc + 3][m] = u.w;
        }
        __syncthreads();
#pragma unroll
        for (int kk = 0; kk < BK; ++kk) {
            float4 a = *reinterpret_cast<const float4*>(&As[kk][ty * 4]);
            float4 b = *reinterpret_cast<const float4*>(&Bs[kk][tx * 4]);
            float av[4] = {a.x, a.y, a.z, a.w};
            float bv[4] = {b.x, b.y, b.z, b.w};
#pragma unroll
            for (int i = 0; i < 4; ++i)
#pragma unroll
                for (int j = 0; j < 4; ++j)
                    acc[i][j] = fmaf(av[i], bv[j], acc[i][j]);
        }
        __syncthreads();
    }

    float4 b4 = *reinterpret_cast<const float4*>(bias + n0 + tx * 4);
    float bb[4] = {b4.x, b4.y, b4.z, b4.w};
#pragma unroll
    for (int i = 0; i < 4; ++i) {
        int m = m0 + ty * 4 + i;
        float4 o;
        o.x = acc[i][0] + bb[0];
        o.y = acc[i][1] + bb[1];
        o.z = acc[i][2] + bb[2];
        o.w = acc[i][3] + bb[3];
        *reinterpret_cast<float4*>(C + (size_t)m * N + n0 + tx * 4) = o;
    }
}

// ---------------- persistent GRU scan v3 ----------------
__device__ __forceinline__ float dot4(float4 a, float4 b) {
    return fmaf(a.x, b.x, fmaf(a.y, b.y, fmaf(a.z, b.z, a.w * b.w)));
}

__global__ __launch_bounds__(SBS, 1)
void gru_scan(const float* __restrict__ gi,    // [T,3H]
              const float* __restrict__ whh,   // [3H,H]
              const float* __restrict__ bhh,   // [3H]
              float* __restrict__ ys,          // [T,H]
              float* __restrict__ hfin,        // [H]
              float* h_buf,                    // [2][H] coherent
              unsigned* flags) {               // [2][GWG*FSTR], zeroed
    const int g    = blockIdx.x;
    const int tid  = threadIdx.x;
    const int slot = tid >> 3;   // 0..63
    const int l8   = tid & 7;

    __shared__ float lds_h[HDIM];
    __shared__ float lds_gh[48];

    // ---- W_hh slice -> registers (static indices) ----
    float4 Wlo[16], Whi[16];
    if (slot < 48) {
        const int q = slot >> 4, jl = slot & 15;
        const float4* row4 = reinterpret_cast<const float4*>(
            whh + (size_t)(q * HDIM + g * 16 + jl) * HDIM);
#pragma unroll
        for (int k4 = 0; k4 < 16; ++k4) Wlo[k4] = row4[k4 * 8 + l8];
#pragma unroll
        for (int k4 = 0; k4 < 16; ++k4) Whi[k4] = row4[(k4 + 16) * 8 + l8];
    } else {
#pragma unroll
        for (int k4 = 0; k4 < 16; ++k4) { Wlo[k4] = float4{0,0,0,0}; Whi[k4] = float4{0,0,0,0}; }
    }

    float bh0 = 0.f, bh1 = 0.f, bh2 = 0.f;
    float gir = 0.f, giz = 0.f, gin = 0.f;
    if (tid < 16) {
        const int gj = g * 16 + tid;
        bh0 = bhh[0 * HDIM + gj];
        bh1 = bhh[1 * HDIM + gj];
        bh2 = bhh[2 * HDIM + gj];
        gir = gi[gj];
        giz = gi[HDIM + gj];
        gin = gi[2 * HDIM + gj];
    }

    lds_h[tid] = 0.f;
    lds_h[tid + SBS] = 0.f;
    __syncthreads();

    const float4* lh4 = reinterpret_cast<const float4*>(lds_h);

    for (int t = 0; t < TT; ++t) {
        // prefetch gi[t+1]
        float nir = 0.f, niz = 0.f, nin = 0.f;
        if (tid < 16 && t + 1 < TT) {
            const float* base = gi + (size_t)(t + 1) * 3 * HDIM + g * 16 + tid;
            nir = base[0];
            niz = base[HDIM];
            nin = base[2 * HDIM];
        }

        // ---- phase A: 48 row-dots ----
        if (slot < 48) {
            float p0 = 0.f, p1 = 0.f;
#pragma unroll
            for (int k4 = 0; k4 < 16; ++k4) p0 += dot4(Wlo[k4], lh4[k4 * 8 + l8]);
#pragma unroll
            for (int k4 = 0; k4 < 16; ++k4) p1 += dot4(Whi[k4], lh4[(k4 + 16) * 8 + l8]);
            float p = p0 + p1;
            p += __shfl_xor(p, 1);
            p += __shfl_xor(p, 2);
            p += __shfl_xor(p, 4);
            if (l8 == 0) lds_gh[slot] = p;
        }
        __syncthreads();   // S1

        // ---- phase B: gates + h store (wave 0, lanes 0..15) ----
        if (tid < 16) {
            const int gj = g * 16 + tid;
            const float hr = lds_gh[tid]      + bh0;
            const float hz = lds_gh[16 + tid] + bh1;
            const float hn = lds_gh[32 + tid] + bh2;
            const float h_old = lds_h[gj];
            const float r = 1.f / (1.f + expf(-(gir + hr)));
            const float z = 1.f / (1.f + expf(-(giz + hz)));
            const float n = tanhf(gin + r * hn);
            const float h_new = (1.f - z) * n + z * h_old;
            __hip_atomic_store(h_buf + ((t + 1) & 1) * HDIM + gj, h_new,
                               __ATOMIC_RELAXED, __HIP_MEMORY_SCOPE_AGENT);
            ys[(size_t)t * HDIM + gj] = h_new;
            if (t == TT - 1) hfin[gj] = h_new;
        }
        // ---- arrive: own flag slot, monotone seq (no RMW) ----
        if (tid == 0) {
            __threadfence();   // drain h stores (same wave) before flag
            __hip_atomic_store(flags + (t & 1) * (GWG * FSTR) + g * FSTR,
                               (unsigned)(t + 1),
                               __ATOMIC_RELAXED, __HIP_MEMORY_SCOPE_AGENT);
        }
        // ---- poll: wave 0, one lane per WG flag ----
        if (tid < GWG) {
            const unsigned* f = flags + (t & 1) * (GWG * FSTR) + tid * FSTR;
            while (__hip_atomic_load(f, __ATOMIC_RELAXED, __HIP_MEMORY_SCOPE_AGENT)
                   < (unsigned)(t + 1))
                __builtin_amdgcn_s_sleep(1);
        }
        __syncthreads();   // S2: all flags seen

        // ---- phase D: pull h_{t+1} into LDS ----
        {
            const unsigned long long hv = __hip_atomic_load(
                reinterpret_cast<const unsigned long long*>(h_buf + ((t + 1) & 1) * HDIM) + tid,
                __ATOMIC_RELAXED, __HIP_MEMORY_SCOPE_AGENT);
            reinterpret_cast<unsigned long long*>(lds_h)[tid] = hv;
        }
        gir = nir; giz = niz; gin = nin;
        __syncthreads();   // S3
    }
}

// ---------------- launch ----------------
extern "C" void kernel_launch(void* const* d_in, const int* in_sizes, int n_in,
                              void* d_out, int out_size, void* d_ws, size_t ws_size,
                              hipStream_t stream) {
    const int*   idx = (const int*)d_in[0];
    const float* emb = (const float*)d_in[1];
    const float* wih = (const float*)d_in[2];
    const float* whh = (const float*)d_in[3];
    const float* bih = (const float*)d_in[4];
    const float* bhh = (const float*)d_in[5];
    float* out = (float*)d_out;

    float* x    = (float*)d_ws;                 // [T,H]
    float* gi   = x   + (size_t)TT * HDIM;      // [T,3H]
    float* ys0  = gi  + (size_t)TT * 3 * HDIM;  // [T,H]
    float* ctrl = ys0 + (size_t)TT * HDIM;
    float* hbuf0 = ctrl;                        // [2,H]
    float* hbuf1 = hbuf0 + 2 * HDIM;            // [2,H]
    unsigned* flags0 = (unsigned*)(hbuf1 + 2 * HDIM);  // [2][GWG*FSTR]
    unsigned* flags1 = flags0 + 2 * GWG * FSTR;        // [2][GWG*FSTR]
    size_t ctrl_bytes = (size_t)(4 * HDIM) * 4 + (size_t)(4 * GWG * FSTR) * 4;

    hipMemsetAsync(ctrl, 0, ctrl_bytes, stream);

    embed_kernel<<<TT, 256, 0, stream>>>(idx, emb, x);

    const size_t wstride = (size_t)3 * HDIM * HDIM;
    const size_t bstride = (size_t)3 * HDIM;

    gemm_nt_bias<<<dim3(TT / BM, 3 * HDIM / BN), 256, 0, stream>>>(
        x, wih, bih, gi, TT, 3 * HDIM, HDIM);
    gru_scan<<<GWG, SBS, 0, stream>>>(gi, whh, bhh, ys0,
                                      out + (size_t)TT * HDIM, hbuf0, flags0);

    gemm_nt_bias<<<dim3(TT / BM, 3 * HDIM / BN), 256, 0, stream>>>(
        ys0, wih + wstride, bih + bstride, gi, TT, 3 * HDIM, HDIM);
    gru_scan<<<GWG, SBS, 0, stream>>>(gi, whh + wstride, bhh + bstride, out,
                                      out + (size_t)TT * HDIM + HDIM, hbuf1, flags1);
}

// Round 4
// 21398.372 us; speedup vs baseline: 4.5146x; 1.3199x over previous
//
#include <hip/hip_runtime.h>
#include <hip/hip_bf16.h>

// 2-layer GRU encoder, T=4096, H=1024.
// v4: embed -> gemm(gi0) -> ONE fused persistent scan, both layers pipelined.
//  - WGs 0..63   : layer 0 (16 h-units each), gi0 precomputed by GEMM.
//  - WGs 64..191 : layer 1 (8 h-units each), computes gi1 on the fly from y0
//    (w_ih1 row slice also VGPR-resident), lags layer 0 by one step.
// Flag-array barriers (per-WG 64B slot, monotone seq). h via agent-scope L3.

#define TT    4096
#define HDIM  1024
#define L0WG  64
#define L1WG  128
#define SBS   512
#define FSTR  16          // flag stride in words (64B)

// ---------------- embedding gather ----------------
__global__ void embed_kernel(const int* __restrict__ idx,
                             const float* __restrict__ emb,
                             float* __restrict__ x) {
    int t = blockIdx.x;
    int row = idx[t];
    const float4* src = reinterpret_cast<const float4*>(emb + (size_t)row * HDIM);
    float4* dst = reinterpret_cast<float4*>(x + (size_t)t * HDIM);
    dst[threadIdx.x] = src[threadIdx.x];
}

// ---------------- fp32 NT GEMM: C[M,N] = A[M,K] * B[N,K]^T + bias[N] ----------------
#define BM 64
#define BN 64
#define BK 32
__global__ __launch_bounds__(256)
void gemm_nt_bias(const float* __restrict__ A,
                  const float* __restrict__ Bw,
                  const float* __restrict__ bias,
                  float* __restrict__ C,
                  int M, int N, int K) {
    __shared__ float As[BK][BM];
    __shared__ float Bs[BK][BN];
    const int tid = threadIdx.x;
    const int m0 = blockIdx.x * BM;
    const int n0 = blockIdx.y * BN;
    const int tx = tid & 15, ty = tid >> 4;
    const int lr = tid >> 3;
    const int lc = (tid & 7) * 4;

    float acc[4][4] = {};

    for (int k0 = 0; k0 < K; k0 += BK) {
#pragma unroll
        for (int pass = 0; pass < 2; ++pass) {
            int m = lr + pass * 32;
            float4 v = *reinterpret_cast<const float4*>(A + (size_t)(m0 + m) * K + k0 + lc);
            As[lc + 0][m] = v.x; As[lc + 1][m] = v.y;
            As[lc + 2][m] = v.z; As[lc + 3][m] = v.w;
            float4 u = *reinterpret_cast<const float4*>(Bw + (size_t)(n0 + m) * K + k0 + lc);
            Bs[lc + 0][m] = u.x; Bs[lc + 1][m] = u.y;
            Bs[lc + 2][m] = u.z; Bs[lc + 3][m] = u.w;
        }
        __syncthreads();
#pragma unroll
        for (int kk = 0; kk < BK; ++kk) {
            float4 a = *reinterpret_cast<const float4*>(&As[kk][ty * 4]);
            float4 b = *reinterpret_cast<const float4*>(&Bs[kk][tx * 4]);
            float av[4] = {a.x, a.y, a.z, a.w};
            float bv[4] = {b.x, b.y, b.z, b.w};
#pragma unroll
            for (int i = 0; i < 4; ++i)
#pragma unroll
                for (int j = 0; j < 4; ++j)
                    acc[i][j] = fmaf(av[i], bv[j], acc[i][j]);
        }
        __syncthreads();
    }

    float4 b4 = *reinterpret_cast<const float4*>(bias + n0 + tx * 4);
    float bb[4] = {b4.x, b4.y, b4.z, b4.w};
#pragma unroll
    for (int i = 0; i < 4; ++i) {
        int m = m0 + ty * 4 + i;
        float4 o;
        o.x = acc[i][0] + bb[0];
        o.y = acc[i][1] + bb[1];
        o.z = acc[i][2] + bb[2];
        o.w = acc[i][3] + bb[3];
        *reinterpret_cast<float4*>(C + (size_t)m * N + n0 + tx * 4) = o;
    }
}

// ---------------- fused pipelined scan ----------------
__device__ __forceinline__ float dot4(float4 a, float4 b) {
    return fmaf(a.x, b.x, fmaf(a.y, b.y, fmaf(a.z, b.z, a.w * b.w)));
}
__device__ __forceinline__ float fsig(float x) {
    return 1.f / (1.f + __expf(-x));
}
__device__ __forceinline__ float ftanh(float x) {
    return fmaf(-2.f, 1.f / (1.f + __expf(2.f * x)), 1.f);
}

__global__ __launch_bounds__(SBS, 1)
void gru_pipe(const float* __restrict__ gi0,   // [T,3H]
              const float* __restrict__ whh0,  // [3H,H]
              const float* __restrict__ bhh0,  // [3H]
              const float* __restrict__ wih1,  // [3H,H]
              const float* __restrict__ whh1,  // [3H,H]
              const float* __restrict__ bih1,  // [3H]
              const float* __restrict__ bhh1,  // [3H]
              float* ys0,                      // [T,H] (ws, agent-coherent use)
              float* __restrict__ out,         // [T*H + 2H]
              float* h0_buf, float* h1_buf,    // [2][H] each
              unsigned* flags0,                // [2][L0WG*FSTR]
              unsigned* flags1) {              // [2][L1WG*FSTR]
    const int tid  = threadIdx.x;
    const int slot = tid >> 3;   // 0..63
    const int l8   = tid & 7;

    __shared__ float lds_h[HDIM];
    __shared__ float lds_y[HDIM];
    __shared__ float lds_gh[48];

    if (blockIdx.x < L0WG) {
        // ================= layer 0 =================
        const int g = blockIdx.x;

        float4 Wlo[16], Whi[16];
        if (slot < 48) {
            const int q = slot >> 4, jl = slot & 15;
            const float4* row4 = reinterpret_cast<const float4*>(
                whh0 + (size_t)(q * HDIM + g * 16 + jl) * HDIM);
#pragma unroll
            for (int k4 = 0; k4 < 16; ++k4) Wlo[k4] = row4[k4 * 8 + l8];
#pragma unroll
            for (int k4 = 0; k4 < 16; ++k4) Whi[k4] = row4[(k4 + 16) * 8 + l8];
        } else {
#pragma unroll
            for (int k4 = 0; k4 < 16; ++k4) { Wlo[k4] = float4{0,0,0,0}; Whi[k4] = float4{0,0,0,0}; }
        }

        float bh0 = 0.f, bh1 = 0.f, bh2 = 0.f;
        float gir = 0.f, giz = 0.f, gin = 0.f;
        if (tid < 16) {
            const int gj = g * 16 + tid;
            bh0 = bhh0[0 * HDIM + gj];
            bh1 = bhh0[1 * HDIM + gj];
            bh2 = bhh0[2 * HDIM + gj];
            gir = gi0[gj];
            giz = gi0[HDIM + gj];
            gin = gi0[2 * HDIM + gj];
        }

        lds_h[tid] = 0.f;
        lds_h[tid + SBS] = 0.f;
        __syncthreads();

        const float4* lh4 = reinterpret_cast<const float4*>(lds_h);

        for (int t = 0; t < TT; ++t) {
            float nir = 0.f, niz = 0.f, nin = 0.f;
            if (tid < 16 && t + 1 < TT) {
                const float* base = gi0 + (size_t)(t + 1) * 3 * HDIM + g * 16 + tid;
                nir = base[0];
                niz = base[HDIM];
                nin = base[2 * HDIM];
            }

            if (slot < 48) {
                float p0 = 0.f, p1 = 0.f;
#pragma unroll
                for (int k4 = 0; k4 < 16; ++k4) p0 += dot4(Wlo[k4], lh4[k4 * 8 + l8]);
#pragma unroll
                for (int k4 = 0; k4 < 16; ++k4) p1 += dot4(Whi[k4], lh4[(k4 + 16) * 8 + l8]);
                float p = p0 + p1;
                p += __shfl_xor(p, 1);
                p += __shfl_xor(p, 2);
                p += __shfl_xor(p, 4);
                if (l8 == 0) lds_gh[slot] = p;
            }
            __syncthreads();

            if (tid < 16) {
                const int gj = g * 16 + tid;
                const float hr = lds_gh[tid]      + bh0;
                const float hz = lds_gh[16 + tid] + bh1;
                const float hn = lds_gh[32 + tid] + bh2;
                const float h_old = lds_h[gj];
                const float r = fsig(gir + hr);
                const float z = fsig(giz + hz);
                const float n = ftanh(gin + r * hn);
                const float h_new = (1.f - z) * n + z * h_old;
                __hip_atomic_store(h0_buf + ((t + 1) & 1) * HDIM + gj, h_new,
                                   __ATOMIC_RELAXED, __HIP_MEMORY_SCOPE_AGENT);
                __hip_atomic_store(ys0 + (size_t)t * HDIM + gj, h_new,
                                   __ATOMIC_RELAXED, __HIP_MEMORY_SCOPE_AGENT);
                if (t == TT - 1) out[(size_t)TT * HDIM + gj] = h_new;
            }
            if (tid == 0) {
                __threadfence();
                __hip_atomic_store(flags0 + (t & 1) * (L0WG * FSTR) + g * FSTR,
                                   (unsigned)(t + 1),
                                   __ATOMIC_RELAXED, __HIP_MEMORY_SCOPE_AGENT);
            }
            if (tid < L0WG) {
                const unsigned* f = flags0 + (t & 1) * (L0WG * FSTR) + tid * FSTR;
                while (__hip_atomic_load(f, __ATOMIC_RELAXED, __HIP_MEMORY_SCOPE_AGENT)
                       < (unsigned)(t + 1))
                    __builtin_amdgcn_s_sleep(1);
            }
            __syncthreads();

            {
                const unsigned long long hv = __hip_atomic_load(
                    reinterpret_cast<const unsigned long long*>(h0_buf + ((t + 1) & 1) * HDIM) + tid,
                    __ATOMIC_RELAXED, __HIP_MEMORY_SCOPE_AGENT);
                reinterpret_cast<unsigned long long*>(lds_h)[tid] = hv;
            }
            gir = nir; giz = niz; gin = nin;
            __syncthreads();
        }
    } else {
        // ================= layer 1 =================
        const int g1 = blockIdx.x - L0WG;   // 0..127, owns units u0 = g1*8..+8

        // slots 0..23: whh1 rows (input lds_h); 24..47: wih1 rows (input lds_y)
        float4 Wlo[16], Whi[16];
        if (slot < 48) {
            const int ss = (slot < 24) ? slot : slot - 24;
            const int q = ss >> 3, jl = ss & 7;
            const float* mat = (slot < 24) ? whh1 : wih1;
            const float4* row4 = reinterpret_cast<const float4*>(
                mat + (size_t)(q * HDIM + g1 * 8 + jl) * HDIM);
#pragma unroll
            for (int k4 = 0; k4 < 16; ++k4) Wlo[k4] = row4[k4 * 8 + l8];
#pragma unroll
            for (int k4 = 0; k4 < 16; ++k4) Whi[k4] = row4[(k4 + 16) * 8 + l8];
        } else {
#pragma unroll
            for (int k4 = 0; k4 < 16; ++k4) { Wlo[k4] = float4{0,0,0,0}; Whi[k4] = float4{0,0,0,0}; }
        }

        float bh0 = 0.f, bh1 = 0.f, bh2 = 0.f;
        float bi0 = 0.f, bi1 = 0.f, bi2 = 0.f;
        if (tid < 8) {
            const int u = g1 * 8 + tid;
            bh0 = bhh1[0 * HDIM + u];
            bh1 = bhh1[1 * HDIM + u];
            bh2 = bhh1[2 * HDIM + u];
            bi0 = bih1[0 * HDIM + u];
            bi1 = bih1[1 * HDIM + u];
            bi2 = bih1[2 * HDIM + u];
        }

        lds_h[tid] = 0.f;
        lds_h[tid + SBS] = 0.f;
        // wait for y0[0], then stage it
        if (tid < L0WG) {
            const unsigned* f = flags0 + 0 * (L0WG * FSTR) + tid * FSTR;
            while (__hip_atomic_load(f, __ATOMIC_RELAXED, __HIP_MEMORY_SCOPE_AGENT) < 1u)
                __builtin_amdgcn_s_sleep(1);
        }
        __syncthreads();
        {
            const unsigned long long yv = __hip_atomic_load(
                reinterpret_cast<const unsigned long long*>(ys0) + tid,
                __ATOMIC_RELAXED, __HIP_MEMORY_SCOPE_AGENT);
            reinterpret_cast<unsigned long long*>(lds_y)[tid] = yv;
        }
        __syncthreads();

        const float4* lh4 = reinterpret_cast<const float4*>(lds_h);
        const float4* ly4 = reinterpret_cast<const float4*>(lds_y);

        for (int t = 0; t < TT; ++t) {
            // phase A: 24 whh rows on lds_h + 24 wih rows on lds_y
            if (slot < 48) {
                const float4* s4 = (slot < 24) ? lh4 : ly4;
                float p0 = 0.f, p1 = 0.f;
#pragma unroll
                for (int k4 = 0; k4 < 16; ++k4) p0 += dot4(Wlo[k4], s4[k4 * 8 + l8]);
#pragma unroll
                for (int k4 = 0; k4 < 16; ++k4) p1 += dot4(Whi[k4], s4[(k4 + 16) * 8 + l8]);
                float p = p0 + p1;
                p += __shfl_xor(p, 1);
                p += __shfl_xor(p, 2);
                p += __shfl_xor(p, 4);
                if (l8 == 0) lds_gh[slot] = p;
            }
            __syncthreads();

            if (tid < 8) {
                const int u = g1 * 8 + tid;
                const float hr = lds_gh[tid]      + bh0;
                const float hz = lds_gh[8 + tid]  + bh1;
                const float hn = lds_gh[16 + tid] + bh2;
                const float ir = lds_gh[24 + tid] + bi0;
                const float iz = lds_gh[32 + tid] + bi1;
                const float in_ = lds_gh[40 + tid] + bi2;
                const float h_old = lds_h[u];
                const float r = fsig(ir + hr);
                const float z = fsig(iz + hz);
                const float n = ftanh(in_ + r * hn);
                const float h_new = (1.f - z) * n + z * h_old;
                __hip_atomic_store(h1_buf + ((t + 1) & 1) * HDIM + u, h_new,
                                   __ATOMIC_RELAXED, __HIP_MEMORY_SCOPE_AGENT);
                out[(size_t)t * HDIM + u] = h_new;
                if (t == TT - 1) out[(size_t)TT * HDIM + HDIM + u] = h_new;
            }
            if (tid == 0) {
                __threadfence();
                __hip_atomic_store(flags1 + (t & 1) * (L1WG * FSTR) + g1 * FSTR,
                                   (unsigned)(t + 1),
                                   __ATOMIC_RELAXED, __HIP_MEMORY_SCOPE_AGENT);
            }
            // poll own flags; in parallel, poll L0 flags for y0[t+1]
            if (tid < L1WG) {
                const unsigned* f = flags1 + (t & 1) * (L1WG * FSTR) + tid * FSTR;
                while (__hip_atomic_load(f, __ATOMIC_RELAXED, __HIP_MEMORY_SCOPE_AGENT)
                       < (unsigned)(t + 1))
                    __builtin_amdgcn_s_sleep(1);
            } else if (tid < L1WG + L0WG && t + 1 < TT) {
                const unsigned* f = flags0 + ((t + 1) & 1) * (L0WG * FSTR) + (tid - L1WG) * FSTR;
                while (__hip_atomic_load(f, __ATOMIC_RELAXED, __HIP_MEMORY_SCOPE_AGENT)
                       < (unsigned)(t + 2))
                    __builtin_amdgcn_s_sleep(1);
            }
            __syncthreads();

            // phase D: stage h1_{t+1} and y0[t+1]
            {
                const unsigned long long hv = __hip_atomic_load(
                    reinterpret_cast<const unsigned long long*>(h1_buf + ((t + 1) & 1) * HDIM) + tid,
                    __ATOMIC_RELAXED, __HIP_MEMORY_SCOPE_AGENT);
                reinterpret_cast<unsigned long long*>(lds_h)[tid] = hv;
                if (t + 1 < TT) {
                    const unsigned long long yv = __hip_atomic_load(
                        reinterpret_cast<const unsigned long long*>(ys0 + (size_t)(t + 1) * HDIM) + tid,
                        __ATOMIC_RELAXED, __HIP_MEMORY_SCOPE_AGENT);
                    reinterpret_cast<unsigned long long*>(lds_y)[tid] = yv;
                }
            }
            __syncthreads();
        }
    }
}

// ---------------- launch ----------------
extern "C" void kernel_launch(void* const* d_in, const int* in_sizes, int n_in,
                              void* d_out, int out_size, void* d_ws, size_t ws_size,
                              hipStream_t stream) {
    const int*   idx = (const int*)d_in[0];
    const float* emb = (const float*)d_in[1];
    const float* wih = (const float*)d_in[2];
    const float* whh = (const float*)d_in[3];
    const float* bih = (const float*)d_in[4];
    const float* bhh = (const float*)d_in[5];
    float* out = (float*)d_out;

    float* x    = (float*)d_ws;                 // [T,H]
    float* gi   = x   + (size_t)TT * HDIM;      // [T,3H]
    float* ys0  = gi  + (size_t)TT * 3 * HDIM;  // [T,H]
    float* ctrl = ys0 + (size_t)TT * HDIM;
    float* hbuf0 = ctrl;                        // [2,H]
    float* hbuf1 = hbuf0 + 2 * HDIM;            // [2,H]
    unsigned* flags0 = (unsigned*)(hbuf1 + 2 * HDIM);  // [2][L0WG*FSTR]
    unsigned* flags1 = flags0 + 2 * L0WG * FSTR;       // [2][L1WG*FSTR]
    size_t ctrl_bytes = (size_t)(4 * HDIM) * 4
                      + (size_t)(2 * L0WG * FSTR + 2 * L1WG * FSTR) * 4;

    hipMemsetAsync(ctrl, 0, ctrl_bytes, stream);

    embed_kernel<<<TT, 256, 0, stream>>>(idx, emb, x);

    const size_t wstride = (size_t)3 * HDIM * HDIM;
    const size_t bstride = (size_t)3 * HDIM;

    // gi for layer 0 only
    gemm_nt_bias<<<dim3(TT / BM, 3 * HDIM / BN), 256, 0, stream>>>(
        x, wih, bih, gi, TT, 3 * HDIM, HDIM);

    gru_pipe<<<L0WG + L1WG, SBS, 0, stream>>>(
        gi, whh, bhh,
        wih + wstride, whh + wstride, bih + bstride, bhh + bstride,
        ys0, out, hbuf0, hbuf1, flags0, flags1);
}

// Round 5
// 16941.882 us; speedup vs baseline: 5.7021x; 1.2630x over previous
//
#include <hip/hip_runtime.h>
#include <hip/hip_bf16.h>

// 2-layer GRU encoder, T=4096, H=1024.
// v5: embed -> gemm(gi0) -> fused pipelined scan (both layers).
// h exchange via TAGGED u64 words: (seq<<32)|bits(h). One relaxed agent-scope
// atomic store publishes; consumers poll the data word itself (poll==load).
// No fence/flag on the h critical path. 2 syncthreads/step. h_old in regs.
// y0 hand-off (layer0 -> layer1) stays flag-based, staged by wave 7 in
// parallel with the h poll (off critical path; layer0 runs ahead).

#define TT    4096
#define HDIM  1024
#define L0WG  64
#define L1WG  128
#define SBS   512
#define FSTR  16          // flag stride in words (64B)

// ---------------- embedding gather ----------------
__global__ void embed_kernel(const int* __restrict__ idx,
                             const float* __restrict__ emb,
                             float* __restrict__ x) {
    int t = blockIdx.x;
    int row = idx[t];
    const float4* src = reinterpret_cast<const float4*>(emb + (size_t)row * HDIM);
    float4* dst = reinterpret_cast<float4*>(x + (size_t)t * HDIM);
    dst[threadIdx.x] = src[threadIdx.x];
}

// ---------------- fp32 NT GEMM: C[M,N] = A[M,K] * B[N,K]^T + bias[N] ----------------
#define BM 64
#define BN 64
#define BK 32
__global__ __launch_bounds__(256)
void gemm_nt_bias(const float* __restrict__ A,
                  const float* __restrict__ Bw,
                  const float* __restrict__ bias,
                  float* __restrict__ C,
                  int M, int N, int K) {
    __shared__ float As[BK][BM];
    __shared__ float Bs[BK][BN];
    const int tid = threadIdx.x;
    const int m0 = blockIdx.x * BM;
    const int n0 = blockIdx.y * BN;
    const int tx = tid & 15, ty = tid >> 4;
    const int lr = tid >> 3;
    const int lc = (tid & 7) * 4;

    float acc[4][4] = {};

    for (int k0 = 0; k0 < K; k0 += BK) {
#pragma unroll
        for (int pass = 0; pass < 2; ++pass) {
            int m = lr + pass * 32;
            float4 v = *reinterpret_cast<const float4*>(A + (size_t)(m0 + m) * K + k0 + lc);
            As[lc + 0][m] = v.x; As[lc + 1][m] = v.y;
            As[lc + 2][m] = v.z; As[lc + 3][m] = v.w;
            float4 u = *reinterpret_cast<const float4*>(Bw + (size_t)(n0 + m) * K + k0 + lc);
            Bs[lc + 0][m] = u.x; Bs[lc + 1][m] = u.y;
            Bs[lc + 2][m] = u.z; Bs[lc + 3][m] = u.w;
        }
        __syncthreads();
#pragma unroll
        for (int kk = 0; kk < BK; ++kk) {
            float4 a = *reinterpret_cast<const float4*>(&As[kk][ty * 4]);
            float4 b = *reinterpret_cast<const float4*>(&Bs[kk][tx * 4]);
            float av[4] = {a.x, a.y, a.z, a.w};
            float bv[4] = {b.x, b.y, b.z, b.w};
#pragma unroll
            for (int i = 0; i < 4; ++i)
#pragma unroll
                for (int j = 0; j < 4; ++j)
                    acc[i][j] = fmaf(av[i], bv[j], acc[i][j]);
        }
        __syncthreads();
    }

    float4 b4 = *reinterpret_cast<const float4*>(bias + n0 + tx * 4);
    float bb[4] = {b4.x, b4.y, b4.z, b4.w};
#pragma unroll
    for (int i = 0; i < 4; ++i) {
        int m = m0 + ty * 4 + i;
        float4 o;
        o.x = acc[i][0] + bb[0];
        o.y = acc[i][1] + bb[1];
        o.z = acc[i][2] + bb[2];
        o.w = acc[i][3] + bb[3];
        *reinterpret_cast<float4*>(C + (size_t)m * N + n0 + tx * 4) = o;
    }
}

// ---------------- fused pipelined scan v5 ----------------
__device__ __forceinline__ float dot4(float4 a, float4 b) {
    return fmaf(a.x, b.x, fmaf(a.y, b.y, fmaf(a.z, b.z, a.w * b.w)));
}
__device__ __forceinline__ float fsig(float x) {
    return 1.f / (1.f + __expf(-x));
}
__device__ __forceinline__ float ftanh(float x) {
    return fmaf(-2.f, 1.f / (1.f + __expf(2.f * x)), 1.f);
}
__device__ __forceinline__ unsigned long long pack_h(unsigned seq, float h) {
    return ((unsigned long long)seq << 32) | (unsigned long long)__float_as_uint(h);
}
__device__ __forceinline__ unsigned long long poll_h(const unsigned long long* p,
                                                     unsigned need) {
    unsigned long long v = __hip_atomic_load(p, __ATOMIC_RELAXED, __HIP_MEMORY_SCOPE_AGENT);
    while ((unsigned)(v >> 32) < need)
        v = __hip_atomic_load(p, __ATOMIC_RELAXED, __HIP_MEMORY_SCOPE_AGENT);
    return v;
}

__global__ __launch_bounds__(SBS, 1)
void gru_pipe(const float* __restrict__ gi0,   // [T,3H]
              const float* __restrict__ whh0,  // [3H,H]
              const float* __restrict__ bhh0,  // [3H]
              const float* __restrict__ wih1,  // [3H,H]
              const float* __restrict__ whh1,  // [3H,H]
              const float* __restrict__ bih1,  // [3H]
              const float* __restrict__ bhh1,  // [3H]
              float* ys0,                      // [T,H] agent-coherent
              float* __restrict__ out,         // [T*H + 2H]
              unsigned long long* h0t,         // [2][H] tagged
              unsigned long long* h1t,         // [2][H] tagged
              unsigned* flags0) {              // [2][L0WG*FSTR]
    const int tid  = threadIdx.x;
    const int slot = tid >> 3;   // 0..63
    const int l8   = tid & 7;

    __shared__ float lds_h[HDIM];
    __shared__ float lds_y[HDIM];
    __shared__ float lds_gh[48];

    if (blockIdx.x < L0WG) {
        // ================= layer 0 =================
        const int g = blockIdx.x;

        float4 Wlo[16], Whi[16];
        if (slot < 48) {
            const int q = slot >> 4, jl = slot & 15;
            const float4* row4 = reinterpret_cast<const float4*>(
                whh0 + (size_t)(q * HDIM + g * 16 + jl) * HDIM);
#pragma unroll
            for (int k4 = 0; k4 < 16; ++k4) Wlo[k4] = row4[k4 * 8 + l8];
#pragma unroll
            for (int k4 = 0; k4 < 16; ++k4) Whi[k4] = row4[(k4 + 16) * 8 + l8];
        } else {
#pragma unroll
            for (int k4 = 0; k4 < 16; ++k4) { Wlo[k4] = float4{0,0,0,0}; Whi[k4] = float4{0,0,0,0}; }
        }

        float bh0 = 0.f, bh1 = 0.f, bh2 = 0.f;
        float gir = 0.f, giz = 0.f, gin = 0.f;
        float h_own = 0.f;
        if (tid < 16) {
            const int gj = g * 16 + tid;
            bh0 = bhh0[0 * HDIM + gj];
            bh1 = bhh0[1 * HDIM + gj];
            bh2 = bhh0[2 * HDIM + gj];
            gir = gi0[gj];
            giz = gi0[HDIM + gj];
            gin = gi0[2 * HDIM + gj];
        }

        lds_h[tid] = 0.f;
        lds_h[tid + SBS] = 0.f;
        __syncthreads();

        const float4* lh4 = reinterpret_cast<const float4*>(lds_h);

        for (int t = 0; t < TT; ++t) {
            // prefetch gi0[t+1]
            float nir = 0.f, niz = 0.f, nin = 0.f;
            if (tid < 16 && t + 1 < TT) {
                const float* base = gi0 + (size_t)(t + 1) * 3 * HDIM + g * 16 + tid;
                nir = base[0];
                niz = base[HDIM];
                nin = base[2 * HDIM];
            }

            // phase A
            if (slot < 48) {
                float p0 = 0.f, p1 = 0.f;
#pragma unroll
                for (int k4 = 0; k4 < 16; ++k4) p0 += dot4(Wlo[k4], lh4[k4 * 8 + l8]);
#pragma unroll
                for (int k4 = 0; k4 < 16; ++k4) p1 += dot4(Whi[k4], lh4[(k4 + 16) * 8 + l8]);
                float p = p0 + p1;
                p += __shfl_xor(p, 1);
                p += __shfl_xor(p, 2);
                p += __shfl_xor(p, 4);
                if (l8 == 0) lds_gh[slot] = p;
            }
            __syncthreads();   // S1

            // phase B (wave0 lanes 0..15): gates; publish tagged h
            if (tid < 16) {
                const int gj = g * 16 + tid;
                const float hr = lds_gh[tid]      + bh0;
                const float hz = lds_gh[16 + tid] + bh1;
                const float hn = lds_gh[32 + tid] + bh2;
                const float r = fsig(gir + hr);
                const float z = fsig(giz + hz);
                const float n = ftanh(gin + r * hn);
                const float h_new = (1.f - z) * n + z * h_own;
                h_own = h_new;
                __hip_atomic_store(h0t + ((t + 1) & 1) * HDIM + gj,
                                   pack_h((unsigned)(t + 1), h_new),
                                   __ATOMIC_RELAXED, __HIP_MEMORY_SCOPE_AGENT);
                __hip_atomic_store(ys0 + (size_t)t * HDIM + gj, h_new,
                                   __ATOMIC_RELAXED, __HIP_MEMORY_SCOPE_AGENT);
                if (t == TT - 1) out[(size_t)TT * HDIM + gj] = h_new;
            }
            // y0-readiness flag for layer 1 (off h critical path)
            if (tid == 0) {
                __threadfence();
                __hip_atomic_store(flags0 + (t & 1) * (L0WG * FSTR) + g * FSTR,
                                   (unsigned)(t + 1),
                                   __ATOMIC_RELAXED, __HIP_MEMORY_SCOPE_AGENT);
            }

            // poll own 2 h units (data-in-tag: poll == load)
            {
                const unsigned need = (unsigned)(t + 1);
                const unsigned long long* hp = h0t + ((t + 1) & 1) * HDIM;
                unsigned long long v0 = poll_h(hp + 2 * tid, need);
                unsigned long long v1 = poll_h(hp + 2 * tid + 1, need);
                float2 hv;
                hv.x = __uint_as_float((unsigned)v0);
                hv.y = __uint_as_float((unsigned)v1);
                reinterpret_cast<float2*>(lds_h)[tid] = hv;
            }
            gir = nir; giz = niz; gin = nin;
            __syncthreads();   // S2
        }
    } else {
        // ================= layer 1 =================
        const int g1 = blockIdx.x - L0WG;   // 0..127, units u = g1*8..+8

        // slots 0..23: whh1 rows; slots 24..47: wih1 rows (8 units each)
        float4 Wlo[16], Whi[16];
        if (slot < 48) {
            const int ss = (slot < 24) ? slot : slot - 24;
            const int q = ss >> 3, jl = ss & 7;
            const float* mat = (slot < 24) ? whh1 : wih1;
            const float4* row4 = reinterpret_cast<const float4*>(
                mat + (size_t)(q * HDIM + g1 * 8 + jl) * HDIM);
#pragma unroll
            for (int k4 = 0; k4 < 16; ++k4) Wlo[k4] = row4[k4 * 8 + l8];
#pragma unroll
            for (int k4 = 0; k4 < 16; ++k4) Whi[k4] = row4[(k4 + 16) * 8 + l8];
        } else {
#pragma unroll
            for (int k4 = 0; k4 < 16; ++k4) { Wlo[k4] = float4{0,0,0,0}; Whi[k4] = float4{0,0,0,0}; }
        }

        float bh0 = 0.f, bh1 = 0.f, bh2 = 0.f;
        float bi0 = 0.f, bi1 = 0.f, bi2 = 0.f;
        float h_own = 0.f;
        if (tid < 8) {
            const int u = g1 * 8 + tid;
            bh0 = bhh1[0 * HDIM + u];
            bh1 = bhh1[1 * HDIM + u];
            bh2 = bhh1[2 * HDIM + u];
            bi0 = bih1[0 * HDIM + u];
            bi1 = bih1[1 * HDIM + u];
            bi2 = bih1[2 * HDIM + u];
        }

        lds_h[tid] = 0.f;
        lds_h[tid + SBS] = 0.f;
        // stage y0[0]: wave 7 waits flags0 then pulls
        if (tid >= 448) {
            const int l = tid - 448;
            const unsigned* f = flags0 + 0 * (L0WG * FSTR) + l * FSTR;
            while (__hip_atomic_load(f, __ATOMIC_RELAXED, __HIP_MEMORY_SCOPE_AGENT) < 1u)
                __builtin_amdgcn_s_sleep(1);
            const unsigned long long* ysrc =
                reinterpret_cast<const unsigned long long*>(ys0) + l * 8;
#pragma unroll
            for (int k = 0; k < 8; ++k) {
                unsigned long long yv = __hip_atomic_load(ysrc + k, __ATOMIC_RELAXED,
                                                          __HIP_MEMORY_SCOPE_AGENT);
                float2 yf;
                yf.x = __uint_as_float((unsigned)yv);
                yf.y = __uint_as_float((unsigned)(yv >> 32));
                reinterpret_cast<float2*>(lds_y)[l * 8 + k] = yf;
            }
        }
        __syncthreads();

        const float4* lh4 = reinterpret_cast<const float4*>(lds_h);
        const float4* ly4 = reinterpret_cast<const float4*>(lds_y);

        for (int t = 0; t < TT; ++t) {
            // phase A: 24 whh rows on lds_h + 24 wih rows on lds_y
            if (slot < 48) {
                const float4* s4 = (slot < 24) ? lh4 : ly4;
                float p0 = 0.f, p1 = 0.f;
#pragma unroll
                for (int k4 = 0; k4 < 16; ++k4) p0 += dot4(Wlo[k4], s4[k4 * 8 + l8]);
#pragma unroll
                for (int k4 = 0; k4 < 16; ++k4) p1 += dot4(Whi[k4], s4[(k4 + 16) * 8 + l8]);
                float p = p0 + p1;
                p += __shfl_xor(p, 1);
                p += __shfl_xor(p, 2);
                p += __shfl_xor(p, 4);
                if (l8 == 0) lds_gh[slot] = p;
            }
            __syncthreads();   // S1

            // phase B (lanes 0..7): gates; publish tagged h1
            if (tid < 8) {
                const int u = g1 * 8 + tid;
                const float hr = lds_gh[tid]      + bh0;
                const float hz = lds_gh[8 + tid]  + bh1;
                const float hn = lds_gh[16 + tid] + bh2;
                const float ir = lds_gh[24 + tid] + bi0;
                const float iz = lds_gh[32 + tid] + bi1;
                const float in_ = lds_gh[40 + tid] + bi2;
                const float r = fsig(ir + hr);
                const float z = fsig(iz + hz);
                const float n = ftanh(in_ + r * hn);
                const float h_new = (1.f - z) * n + z * h_own;
                h_own = h_new;
                __hip_atomic_store(h1t + ((t + 1) & 1) * HDIM + u,
                                   pack_h((unsigned)(t + 1), h_new),
                                   __ATOMIC_RELAXED, __HIP_MEMORY_SCOPE_AGENT);
                out[(size_t)t * HDIM + u] = h_new;
                if (t == TT - 1) out[(size_t)TT * HDIM + HDIM + u] = h_new;
            }

            // wave 7: stage y0[t+1] (flag poll + pull), parallel with h poll
            if (tid >= 448 && t + 1 < TT) {
                const int l = tid - 448;
                const unsigned* f = flags0 + ((t + 1) & 1) * (L0WG * FSTR) + l * FSTR;
                while (__hip_atomic_load(f, __ATOMIC_RELAXED, __HIP_MEMORY_SCOPE_AGENT)
                       < (unsigned)(t + 2)) { }
                const unsigned long long* ysrc =
                    reinterpret_cast<const unsigned long long*>(ys0 + (size_t)(t + 1) * HDIM) + l * 8;
#pragma unroll
                for (int k = 0; k < 8; ++k) {
                    unsigned long long yv = __hip_atomic_load(ysrc + k, __ATOMIC_RELAXED,
                                                              __HIP_MEMORY_SCOPE_AGENT);
                    float2 yf;
                    yf.x = __uint_as_float((unsigned)yv);
                    yf.y = __uint_as_float((unsigned)(yv >> 32));
                    reinterpret_cast<float2*>(lds_y)[l * 8 + k] = yf;
                }
            }

            // all threads: poll own 2 h1 units
            {
                const unsigned need = (unsigned)(t + 1);
                const unsigned long long* hp = h1t + ((t + 1) & 1) * HDIM;
                unsigned long long v0 = poll_h(hp + 2 * tid, need);
                unsigned long long v1 = poll_h(hp + 2 * tid + 1, need);
                float2 hv;
                hv.x = __uint_as_float((unsigned)v0);
                hv.y = __uint_as_float((unsigned)v1);
                reinterpret_cast<float2*>(lds_h)[tid] = hv;
            }
            __syncthreads();   // S2
        }
    }
}

// ---------------- launch ----------------
extern "C" void kernel_launch(void* const* d_in, const int* in_sizes, int n_in,
                              void* d_out, int out_size, void* d_ws, size_t ws_size,
                              hipStream_t stream) {
    const int*   idx = (const int*)d_in[0];
    const float* emb = (const float*)d_in[1];
    const float* wih = (const float*)d_in[2];
    const float* whh = (const float*)d_in[3];
    const float* bih = (const float*)d_in[4];
    const float* bhh = (const float*)d_in[5];
    float* out = (float*)d_out;

    float* x    = (float*)d_ws;                 // [T,H]
    float* gi   = x   + (size_t)TT * HDIM;      // [T,3H]
    float* ys0  = gi  + (size_t)TT * 3 * HDIM;  // [T,H]
    float* ctrl = ys0 + (size_t)TT * HDIM;
    unsigned long long* h0t = (unsigned long long*)ctrl;   // [2][H]
    unsigned long long* h1t = h0t + 2 * HDIM;              // [2][H]
    unsigned* flags0 = (unsigned*)(h1t + 2 * HDIM);        // [2][L0WG*FSTR]
    size_t ctrl_bytes = (size_t)(4 * HDIM) * 8 + (size_t)(2 * L0WG * FSTR) * 4;

    hipMemsetAsync(ctrl, 0, ctrl_bytes, stream);

    embed_kernel<<<TT, 256, 0, stream>>>(idx, emb, x);

    const size_t wstride = (size_t)3 * HDIM * HDIM;
    const size_t bstride = (size_t)3 * HDIM;

    gemm_nt_bias<<<dim3(TT / BM, 3 * HDIM / BN), 256, 0, stream>>>(
        x, wih, bih, gi, TT, 3 * HDIM, HDIM);

    gru_pipe<<<L0WG + L1WG, SBS, 0, stream>>>(
        gi, whh, bhh,
        wih + wstride, whh + wstride, bih + bstride, bhh + bstride,
        ys0, out, h0t, h1t, flags0);
}